// Round 1
// baseline (1938.362 us; speedup 1.0000x reference)
//
#include <hip/hip_runtime.h>
#include <hip/hip_bf16.h>
#include <stdint.h>

#define T_TOK 16384
#define HDIM  1024
#define IDIM  4096
#define NEXP  8

typedef __bf16  bf16x8  __attribute__((ext_vector_type(8)));
typedef float   floatx4 __attribute__((ext_vector_type(4)));

__device__ __forceinline__ void gload16(const void* g, void* lds) {
  __builtin_amdgcn_global_load_lds(
      (__attribute__((address_space(1))) void*)g,
      (__attribute__((address_space(3))) void*)lds, 16, 0, 0);
}

// ---------------- fp32 -> bf16 convert, 8 elems/thread ----------------
__global__ __launch_bounds__(256) void cvtk(const float* __restrict__ s,
                                            __bf16* __restrict__ d, int n8) {
  int i = blockIdx.x * 256 + threadIdx.x;
  if (i >= n8) return;
  const float4* s4 = (const float4*)s;
  float4 a = s4[2 * i], b = s4[2 * i + 1];
  bf16x8 v;
  v[0] = (__bf16)a.x; v[1] = (__bf16)a.y; v[2] = (__bf16)a.z; v[3] = (__bf16)a.w;
  v[4] = (__bf16)b.x; v[5] = (__bf16)b.y; v[6] = (__bf16)b.z; v[7] = (__bf16)b.w;
  *(bf16x8*)(d + (size_t)i * 8) = v;
}

// ---------------- router: fp32 logits, top-2, histogram ----------------
__global__ __launch_bounds__(256) void routerk(const float* __restrict__ x,
    const float* __restrict__ Wg, float* __restrict__ logits,
    int* __restrict__ topk_e, float* __restrict__ topk_g,
    int* __restrict__ gcount) {
  int wv = threadIdx.x >> 6, ln = threadIdx.x & 63;
  int t = blockIdx.x * 4 + wv;
  const float* xr = x + (size_t)t * HDIM;
  float acc[NEXP];
#pragma unroll
  for (int e = 0; e < NEXP; e++) acc[e] = 0.f;
  for (int h = ln; h < HDIM; h += 64) {
    float xv = xr[h];
#pragma unroll
    for (int e = 0; e < NEXP; e++) acc[e] += xv * Wg[e * HDIM + h];
  }
#pragma unroll
  for (int e = 0; e < NEXP; e++) {
#pragma unroll
    for (int off = 32; off > 0; off >>= 1) acc[e] += __shfl_down(acc[e], off);
  }
  if (ln == 0) {
#pragma unroll
    for (int e = 0; e < NEXP; e++) logits[(size_t)t * NEXP + e] = acc[e];
    int i0 = 0;
#pragma unroll
    for (int e = 1; e < NEXP; e++) if (acc[e] > acc[i0]) i0 = e;
    int i1 = (i0 == 0) ? 1 : 0;
#pragma unroll
    for (int e = 0; e < NEXP; e++)
      if (e != i0 && e != i1 && acc[e] > acc[i1]) i1 = e;
    float r = expf(acc[i1] - acc[i0]);
    float s = 1.f + r;
    topk_e[2 * t] = i0;     topk_g[2 * t] = 1.f / s;
    topk_e[2 * t + 1] = i1; topk_g[2 * t + 1] = r / s;
    atomicAdd(&gcount[i0], 1);
    atomicAdd(&gcount[i1], 1);
  }
}

// ---------------- prefix + block tables (single thread, tiny) ----------------
__global__ void prefixk(const int* __restrict__ gcount, int* __restrict__ goff,
                        int* __restrict__ gcur, int* __restrict__ tbl,
                        int* __restrict__ ntb, int CH) {
  if (threadIdx.x != 0 || blockIdx.x != 0) return;
  int s = 0;
  for (int g = 0; g < NEXP; g++) { goff[g] = s; gcur[g] = s; s += gcount[g]; }
  goff[NEXP] = s;
  int chunk_rows = (2 * T_TOK) / CH;
  int cnt[16];
  for (int c = 0; c < CH; c++) cnt[c] = 0;
  for (int g = 0; g < NEXP; g++) {
    int Ne = goff[g + 1] - goff[g];
    int nb = (Ne + 127) >> 7;
    for (int b = 0; b < nb; b++) {
      int gr0 = goff[g] + b * 128;
      int c = gr0 / chunk_rows;
      tbl[c * 288 + cnt[c]] = (g << 8) | b;
      cnt[c]++;
    }
  }
  for (int c = 0; c < CH; c++) ntb[c] = cnt[c];
}

// ---------------- scatter tokens into compact per-expert lists ----------------
__global__ __launch_bounds__(256) void scatterk(const int* __restrict__ topk_e,
    const float* __restrict__ topk_g, int* __restrict__ gcur,
    int* __restrict__ row_info, float* __restrict__ row_gate) {
  int t = blockIdx.x * 256 + threadIdx.x;
  if (t >= T_TOK) return;
#pragma unroll
  for (int k = 0; k < 2; k++) {
    int e = topk_e[2 * t + k];
    int pos = atomicAdd(&gcur[e], 1);
    row_info[pos] = t;
    row_gate[pos] = topk_g[2 * t + k];
  }
}

// ============================================================================
// GEMM core structure (both gemms):
//   128x128 tile, 4 waves, BK=32, 16x16x32 bf16 MFMA.
//   NEW: depth-3 prefetch pipeline over 4 LDS buffers (16KB each, 64KB total)
//        with raw s_barrier + counted s_waitcnt vmcnt(8) (T3/T4) — loads get
//        ~3 iterations to cover HBM latency; never drain vmcnt to 0 in loop.
//   NEW: T2 XOR swizzle to kill the 8-way ds_read_b128 bank conflict of the
//        stride-64B row layout. global_load_lds dest stays LINEAR; the global
//        SOURCE column is pre-swizzled (col16 ^= (row>>1)&3, an involution)
//        and the frag-read base applies the same XOR — constant per lane.
// ============================================================================

// ---------------- GEMM1: hmid = silu(x @ W1[e]^T + b1[e]), bf16 out ----------------
__global__ __launch_bounds__(256) void gemm1k(
    const __bf16* __restrict__ xb, const __bf16* __restrict__ w1b,
    const float* __restrict__ b1, __bf16* __restrict__ hmid,
    const int* __restrict__ row_info, const int* __restrict__ goff,
    const int* __restrict__ tbl, const int* __restrict__ ntb, int chunk_base) {
  __shared__ __attribute__((aligned(16))) char smem[65536];
  if ((int)blockIdx.x >= ntb[0]) return;
  int info = tbl[blockIdx.x];
  int g = info >> 8, br = info & 255;
  int base = goff[g];
  int Ne = goff[g + 1] - base;
  int r0 = br * 128;
  if (r0 >= Ne) return;
  int n0 = blockIdx.y * 128;
  int tid = threadIdx.x, w = tid >> 6, ln = tid & 63;
  int ra = w * 32 + (ln >> 2);
  // pre-swizzled global source column: row-in-group = ln>>2, (row>>1)&3 = (ln>>3)&3
  int cs = (((ln & 3) ^ ((ln >> 3) & 3)) * 16);
  int rA0 = r0 + ra;      if (rA0 > Ne - 1) rA0 = Ne - 1;
  int rA1 = r0 + ra + 16; if (rA1 > Ne - 1) rA1 = Ne - 1;
  int t0 = row_info[base + rA0];
  int t1 = row_info[base + rA1];
  const char* gA0 = (const char*)(xb + (size_t)t0 * HDIM) + cs;
  const char* gA1 = (const char*)(xb + (size_t)t1 * HDIM) + cs;
  const char* gB0 = (const char*)(w1b + (size_t)g * IDIM * HDIM + (size_t)(n0 + ra) * HDIM) + cs;
  const char* gB1 = (const char*)(w1b + (size_t)g * IDIM * HDIM + (size_t)(n0 + ra + 16) * HDIM) + cs;
  int aoff = w * 2048;
  int boff = 8192 + w * 2048;
  int lm = ln & 15, lq = ln >> 4;
  // swizzled read base: same involution, constant per lane ((row>>1)&3 = (lm>>1)&3)
  int sw = (lq ^ ((lm >> 1) & 3)) * 16;
  int rdA = ((w >> 1) * 64 + lm) * 64 + sw;
  int rdB = 8192 + ((w & 1) * 64 + lm) * 64 + sw;
  floatx4 acc[4][4] = {};

  auto compute = [&](int kt) {
    const char* cbuf = smem + (kt & 3) * 16384;
    bf16x8 af[4], bfv[4];
#pragma unroll
    for (int mi = 0; mi < 4; mi++) af[mi] = *(const bf16x8*)(cbuf + rdA + mi * 1024);
#pragma unroll
    for (int ni = 0; ni < 4; ni++) bfv[ni] = *(const bf16x8*)(cbuf + rdB + ni * 1024);
#pragma unroll
    for (int mi = 0; mi < 4; mi++)
#pragma unroll
      for (int ni = 0; ni < 4; ni++)
        acc[mi][ni] = __builtin_amdgcn_mfma_f32_16x16x32_bf16(af[mi], bfv[ni], acc[mi][ni], 0, 0, 0);
  };

  const int NK = HDIM / 32;
  // prologue: issue tiles 0..2
#pragma unroll
  for (int p = 0; p < 3; p++) {
    int kb = p * 64;
    char* nb = smem + p * 16384;
    gload16(gA0 + kb, nb + aoff);
    gload16(gA1 + kb, nb + aoff + 1024);
    gload16(gB0 + kb, nb + boff);
    gload16(gB1 + kb, nb + boff + 1024);
  }
  int kt = 0;
#pragma unroll 2
  for (; kt < NK - 2; kt++) {
    // tiles kt..kt+2 in flight (12 vm ops) -> wait to 8 = tile kt landed
    asm volatile("s_waitcnt vmcnt(8) lgkmcnt(0)" ::: "memory");
    __builtin_amdgcn_s_barrier();
    asm volatile("" ::: "memory");
    if (kt + 3 < NK) {
      int kb = (kt + 3) * 64;
      char* nb = smem + ((kt + 3) & 3) * 16384;  // == (kt-1)&3, freed by barrier
      gload16(gA0 + kb, nb + aoff);
      gload16(gA1 + kb, nb + aoff + 1024);
      gload16(gB0 + kb, nb + boff);
      gload16(gB1 + kb, nb + boff + 1024);
    }
    compute(kt);
  }
  asm volatile("s_waitcnt vmcnt(4) lgkmcnt(0)" ::: "memory");
  __builtin_amdgcn_s_barrier();
  asm volatile("" ::: "memory");
  compute(NK - 2);
  asm volatile("s_waitcnt vmcnt(0) lgkmcnt(0)" ::: "memory");
  __builtin_amdgcn_s_barrier();
  asm volatile("" ::: "memory");
  compute(NK - 1);

  int colbase = n0 + (w & 1) * 64;
#pragma unroll
  for (int mi = 0; mi < 4; mi++) {
#pragma unroll
    for (int reg = 0; reg < 4; reg++) {
      int rr = r0 + (w >> 1) * 64 + mi * 16 + lq * 4 + reg;
      if (rr < Ne) {
        __bf16* orow = hmid + (size_t)(base + rr - chunk_base) * IDIM;
#pragma unroll
        for (int ni = 0; ni < 4; ni++) {
          int c = colbase + ni * 16 + lm;
          float v = acc[mi][ni][reg] + b1[g * IDIM + c];
          v = v / (1.f + __expf(-v));
          orow[c] = (__bf16)v;
        }
      }
    }
  }
}

// ---------------- GEMM2: out += gate * (hmid @ W2[e]^T + b2[e]) ----------------
__global__ __launch_bounds__(256) void gemm2k(
    const __bf16* __restrict__ hmid, const __bf16* __restrict__ w2b,
    const float* __restrict__ b2, float* __restrict__ out,
    const int* __restrict__ row_info, const float* __restrict__ row_gate,
    const int* __restrict__ goff, const int* __restrict__ tbl,
    const int* __restrict__ ntb, int chunk_base) {
  __shared__ __attribute__((aligned(16))) char smem[65536];
  if ((int)blockIdx.x >= ntb[0]) return;
  int info = tbl[blockIdx.x];
  int g = info >> 8, br = info & 255;
  int base = goff[g];
  int Ne = goff[g + 1] - base;
  int r0 = br * 128;
  if (r0 >= Ne) return;
  int n0 = blockIdx.y * 128;
  int tid = threadIdx.x, w = tid >> 6, ln = tid & 63;
  int ra = w * 32 + (ln >> 2);
  int cs = (((ln & 3) ^ ((ln >> 3) & 3)) * 16);
  int rA0 = r0 + ra;      if (rA0 > Ne - 1) rA0 = Ne - 1;
  int rA1 = r0 + ra + 16; if (rA1 > Ne - 1) rA1 = Ne - 1;
  const char* gA0 = (const char*)(hmid + (size_t)(base + rA0 - chunk_base) * IDIM) + cs;
  const char* gA1 = (const char*)(hmid + (size_t)(base + rA1 - chunk_base) * IDIM) + cs;
  const char* gB0 = (const char*)(w2b + (size_t)g * HDIM * IDIM + (size_t)(n0 + ra) * IDIM) + cs;
  const char* gB1 = (const char*)(w2b + (size_t)g * HDIM * IDIM + (size_t)(n0 + ra + 16) * IDIM) + cs;
  int aoff = w * 2048;
  int boff = 8192 + w * 2048;
  int lm = ln & 15, lq = ln >> 4;
  int sw = (lq ^ ((lm >> 1) & 3)) * 16;
  int rdA = ((w >> 1) * 64 + lm) * 64 + sw;
  int rdB = 8192 + ((w & 1) * 64 + lm) * 64 + sw;
  floatx4 acc[4][4] = {};

  auto compute = [&](int kt) {
    const char* cbuf = smem + (kt & 3) * 16384;
    bf16x8 af[4], bfv[4];
#pragma unroll
    for (int mi = 0; mi < 4; mi++) af[mi] = *(const bf16x8*)(cbuf + rdA + mi * 1024);
#pragma unroll
    for (int ni = 0; ni < 4; ni++) bfv[ni] = *(const bf16x8*)(cbuf + rdB + ni * 1024);
#pragma unroll
    for (int mi = 0; mi < 4; mi++)
#pragma unroll
      for (int ni = 0; ni < 4; ni++)
        acc[mi][ni] = __builtin_amdgcn_mfma_f32_16x16x32_bf16(af[mi], bfv[ni], acc[mi][ni], 0, 0, 0);
  };

  const int NK = IDIM / 32;
#pragma unroll
  for (int p = 0; p < 3; p++) {
    int kb = p * 64;
    char* nb = smem + p * 16384;
    gload16(gA0 + kb, nb + aoff);
    gload16(gA1 + kb, nb + aoff + 1024);
    gload16(gB0 + kb, nb + boff);
    gload16(gB1 + kb, nb + boff + 1024);
  }
  int kt = 0;
#pragma unroll 2
  for (; kt < NK - 2; kt++) {
    asm volatile("s_waitcnt vmcnt(8) lgkmcnt(0)" ::: "memory");
    __builtin_amdgcn_s_barrier();
    asm volatile("" ::: "memory");
    if (kt + 3 < NK) {
      int kb = (kt + 3) * 64;
      char* nb = smem + ((kt + 3) & 3) * 16384;
      gload16(gA0 + kb, nb + aoff);
      gload16(gA1 + kb, nb + aoff + 1024);
      gload16(gB0 + kb, nb + boff);
      gload16(gB1 + kb, nb + boff + 1024);
    }
    compute(kt);
  }
  asm volatile("s_waitcnt vmcnt(4) lgkmcnt(0)" ::: "memory");
  __builtin_amdgcn_s_barrier();
  asm volatile("" ::: "memory");
  compute(NK - 2);
  asm volatile("s_waitcnt vmcnt(0) lgkmcnt(0)" ::: "memory");
  __builtin_amdgcn_s_barrier();
  asm volatile("" ::: "memory");
  compute(NK - 1);

  int colbase = n0 + (w & 1) * 64;
#pragma unroll
  for (int mi = 0; mi < 4; mi++) {
#pragma unroll
    for (int reg = 0; reg < 4; reg++) {
      int rr = r0 + (w >> 1) * 64 + mi * 16 + lq * 4 + reg;
      if (rr < Ne) {
        int t = row_info[base + rr];
        float gate = row_gate[base + rr];
        float* orow = out + (size_t)t * HDIM;
#pragma unroll
        for (int ni = 0; ni < 4; ni++) {
          int c = colbase + ni * 16 + lm;
          float v = gate * (acc[mi][ni][reg] + b2[g * HDIM + c]);
          atomicAdd(&orow[c], v);
        }
      }
    }
  }
}

extern "C" void kernel_launch(void* const* d_in, const int* in_sizes, int n_in,
                              void* d_out, int out_size, void* d_ws, size_t ws_size,
                              hipStream_t stream) {
  (void)in_sizes; (void)n_in; (void)out_size;
  const float* x  = (const float*)d_in[0];
  const float* Wg = (const float*)d_in[1];
  const float* W1 = (const float*)d_in[2];
  const float* b1 = (const float*)d_in[3];
  const float* W2 = (const float*)d_in[4];
  const float* b2 = (const float*)d_in[5];
  float* out = (float*)d_out;
  float* logits = out + (size_t)T_TOK * HDIM;

  const size_t xb_b   = (size_t)T_TOK * HDIM * 2;
  const size_t w_b    = (size_t)NEXP * IDIM * HDIM * 2;
  const size_t side_b = (size_t)2 * T_TOK * 4;
  const size_t meta_b = 32768;
  // CH=2: hmid chunk = ~134MB -> stays resident in the 256MB Infinity Cache
  // between gemm1 (producer) and gemm2's 8 column passes (consumer).
  int CH = 2;
  while (CH < 16) {
    size_t hm = ((size_t)((2 * T_TOK) / CH) + 128) * IDIM * 2;
    size_t need = xb_b + 2 * w_b + hm + 4 * side_b + meta_b + 8192;
    if (need <= ws_size) break;
    CH *= 2;
  }
  const int R = (2 * T_TOK) / CH;

  char* p = (char*)d_ws;
  size_t off = 0;
  auto take = [&](size_t bytes) -> char* {
    char* r = p + off;
    off = (off + bytes + 255) & ~(size_t)255;
    return r;
  };
  __bf16* xb   = (__bf16*)take(xb_b);
  __bf16* w1b  = (__bf16*)take(w_b);
  __bf16* w2b  = (__bf16*)take(w_b);
  __bf16* hmid = (__bf16*)take(((size_t)R + 128) * IDIM * 2);
  int*   topk_e   = (int*)take(side_b);
  float* topk_g   = (float*)take(side_b);
  int*   row_info = (int*)take(side_b);
  float* row_gate = (float*)take(side_b);
  int*   gcount   = (int*)take(16 * 4);
  int*   goff     = (int*)take(17 * 4);
  int*   gcur     = (int*)take(16 * 4);
  int*   ntb      = (int*)take(16 * 4);
  int*   tbl      = (int*)take(16 * 288 * 4);

  hipMemsetAsync(gcount, 0, 16 * 4, stream);
  hipMemsetAsync(out, 0, (size_t)T_TOK * HDIM * 4, stream);

  cvtk<<<(T_TOK * HDIM / 8) / 256, 256, 0, stream>>>(x, xb, T_TOK * HDIM / 8);
  cvtk<<<(NEXP * IDIM * HDIM / 8) / 256, 256, 0, stream>>>(W1, w1b, NEXP * IDIM * HDIM / 8);
  cvtk<<<(NEXP * IDIM * HDIM / 8) / 256, 256, 0, stream>>>(W2, w2b, NEXP * IDIM * HDIM / 8);
  routerk<<<T_TOK / 4, 256, 0, stream>>>(x, Wg, logits, topk_e, topk_g, gcount);
  prefixk<<<1, 64, 0, stream>>>(gcount, goff, gcur, tbl, ntb, CH);
  scatterk<<<T_TOK / 256, 256, 0, stream>>>(topk_e, topk_g, gcur, row_info, row_gate);

  int gx = R / 128 + 8;
  for (int c = 0; c < CH; c++) {
    gemm1k<<<dim3(gx, IDIM / 128, 1), 256, 0, stream>>>(
        xb, w1b, b1, hmid, row_info, goff, tbl + c * 288, ntb + c, c * R);
    gemm2k<<<dim3(gx, HDIM / 128, 1), 256, 0, stream>>>(
        hmid, w2b, b2, out, row_info, row_gate, goff, tbl + c * 288, ntb + c, c * R);
  }
}

// Round 2
// 1518.653 us; speedup vs baseline: 1.2764x; 1.2764x over previous
//
#include <hip/hip_runtime.h>
#include <hip/hip_bf16.h>
#include <stdint.h>

#define T_TOK 16384
#define HDIM  1024
#define IDIM  4096
#define NEXP  8

typedef __bf16  bf16x8  __attribute__((ext_vector_type(8)));
typedef float   floatx4 __attribute__((ext_vector_type(4)));

__device__ __forceinline__ void gload16(const void* g, void* lds) {
  __builtin_amdgcn_global_load_lds(
      (__attribute__((address_space(1))) void*)g,
      (__attribute__((address_space(3))) void*)lds, 16, 0, 0);
}

// ---------------- fp32 -> bf16 convert, 8 elems/thread ----------------
__global__ __launch_bounds__(256) void cvtk(const float* __restrict__ s,
                                            __bf16* __restrict__ d, int n8) {
  int i = blockIdx.x * 256 + threadIdx.x;
  if (i >= n8) return;
  const float4* s4 = (const float4*)s;
  float4 a = s4[2 * i], b = s4[2 * i + 1];
  bf16x8 v;
  v[0] = (__bf16)a.x; v[1] = (__bf16)a.y; v[2] = (__bf16)a.z; v[3] = (__bf16)a.w;
  v[4] = (__bf16)b.x; v[5] = (__bf16)b.y; v[6] = (__bf16)b.z; v[7] = (__bf16)b.w;
  *(bf16x8*)(d + (size_t)i * 8) = v;
}

// ---------------- router: fp32 logits, top-2, per-block LDS histogram ----------------
// OLD: 2 atomicAdds per wave on 8 counters in ONE cacheline -> 32768 contended
// TCC atomics serialized the kernel at 392us (VALUBusy 4%, BW 1%).
// NEW: 64 tokens/block, LDS histogram, 8 global atomics per block (2048 total).
__global__ __launch_bounds__(256) void routerk(const float* __restrict__ x,
    const float* __restrict__ Wg, float* __restrict__ logits,
    int* __restrict__ topk_e, float* __restrict__ topk_g,
    int* __restrict__ gcount) {
  __shared__ int hist[NEXP];
  int tid = threadIdx.x;
  if (tid < NEXP) hist[tid] = 0;
  __syncthreads();
  int wv = tid >> 6, ln = tid & 63;
  for (int it = 0; it < 16; ++it) {
    int t = blockIdx.x * 64 + wv * 16 + it;
    const float* xr = x + (size_t)t * HDIM;
    float acc[NEXP];
#pragma unroll
    for (int e = 0; e < NEXP; e++) acc[e] = 0.f;
    for (int h = ln; h < HDIM; h += 64) {
      float xv = xr[h];
#pragma unroll
      for (int e = 0; e < NEXP; e++) acc[e] += xv * Wg[e * HDIM + h];
    }
#pragma unroll
    for (int e = 0; e < NEXP; e++) {
#pragma unroll
      for (int off = 32; off > 0; off >>= 1) acc[e] += __shfl_down(acc[e], off);
    }
    if (ln == 0) {
#pragma unroll
      for (int e = 0; e < NEXP; e++) logits[(size_t)t * NEXP + e] = acc[e];
      int i0 = 0;
#pragma unroll
      for (int e = 1; e < NEXP; e++) if (acc[e] > acc[i0]) i0 = e;
      int i1 = (i0 == 0) ? 1 : 0;
#pragma unroll
      for (int e = 0; e < NEXP; e++)
        if (e != i0 && e != i1 && acc[e] > acc[i1]) i1 = e;
      float r = expf(acc[i1] - acc[i0]);
      float s = 1.f + r;
      topk_e[2 * t] = i0;     topk_g[2 * t] = 1.f / s;
      topk_e[2 * t + 1] = i1; topk_g[2 * t + 1] = r / s;
      atomicAdd(&hist[i0], 1);
      atomicAdd(&hist[i1], 1);
    }
  }
  __syncthreads();
  if (tid < NEXP) atomicAdd(&gcount[tid], hist[tid]);
}

// ---------------- prefix + block tables (single thread, tiny) ----------------
__global__ void prefixk(const int* __restrict__ gcount, int* __restrict__ goff,
                        int* __restrict__ gcur, int* __restrict__ tbl,
                        int* __restrict__ ntb, int CH) {
  if (threadIdx.x != 0 || blockIdx.x != 0) return;
  int s = 0;
  for (int g = 0; g < NEXP; g++) { goff[g] = s; gcur[g] = s; s += gcount[g]; }
  goff[NEXP] = s;
  int chunk_rows = (2 * T_TOK) / CH;
  int cnt[16];
  for (int c = 0; c < CH; c++) cnt[c] = 0;
  for (int g = 0; g < NEXP; g++) {
    int Ne = goff[g + 1] - goff[g];
    int nb = (Ne + 127) >> 7;
    for (int b = 0; b < nb; b++) {
      int gr0 = goff[g] + b * 128;
      int c = gr0 / chunk_rows;
      tbl[c * 288 + cnt[c]] = (g << 8) | b;
      cnt[c]++;
    }
  }
  for (int c = 0; c < CH; c++) ntb[c] = cnt[c];
}

// ---------------- scatter: per-block LDS histogram + block-range reservation ----------------
// OLD: 32768 contended atomics on gcur (one cacheline) ~ est. 300us.
// NEW: LDS-local offsets, one range-reserving atomic per expert per block (512 total).
__global__ __launch_bounds__(256) void scatterk(const int* __restrict__ topk_e,
    const float* __restrict__ topk_g, int* __restrict__ gcur,
    int* __restrict__ row_info, float* __restrict__ row_gate) {
  __shared__ int hist[NEXP];
  __shared__ int bbase[NEXP];
  int tid = threadIdx.x;
  if (tid < NEXP) hist[tid] = 0;
  __syncthreads();
  int t = blockIdx.x * 256 + tid;
  int e0 = topk_e[2 * t], e1 = topk_e[2 * t + 1];
  float g0 = topk_g[2 * t], g1 = topk_g[2 * t + 1];
  int l0 = atomicAdd(&hist[e0], 1);
  int l1 = atomicAdd(&hist[e1], 1);
  __syncthreads();
  if (tid < NEXP) bbase[tid] = atomicAdd(&gcur[tid], hist[tid]);
  __syncthreads();
  int p0 = bbase[e0] + l0;
  row_info[p0] = t; row_gate[p0] = g0;
  int p1 = bbase[e1] + l1;
  row_info[p1] = t; row_gate[p1] = g1;
}

// ---------------- GEMM1: hmid = silu(x @ W1[e]^T + b1[e]), bf16 out ----------------
// Round-0 proven structure: double-buffered LDS (32KB), one __syncthreads/iter,
// prefetch issued right after the barrier. (Explicit depth-3 counted-vmcnt
// pipeline was neutral-to-negative: occupancy 3->2 blocks/CU cost cancelled it,
// matching the documented m97-structure ceiling behavior.)
__global__ __launch_bounds__(256) void gemm1k(
    const __bf16* __restrict__ xb, const __bf16* __restrict__ w1b,
    const float* __restrict__ b1, __bf16* __restrict__ hmid,
    const int* __restrict__ row_info, const int* __restrict__ goff,
    const int* __restrict__ tbl, const int* __restrict__ ntb, int chunk_base) {
  __shared__ __attribute__((aligned(16))) char smem[32768];
  if ((int)blockIdx.x >= ntb[0]) return;
  int info = tbl[blockIdx.x];
  int g = info >> 8, br = info & 255;
  int base = goff[g];
  int Ne = goff[g + 1] - base;
  int r0 = br * 128;
  if (r0 >= Ne) return;
  int n0 = blockIdx.y * 128;
  int tid = threadIdx.x, w = tid >> 6, ln = tid & 63;
  int ra = w * 32 + (ln >> 2);
  int ca = (ln & 3) * 16;
  int rA0 = r0 + ra;      if (rA0 > Ne - 1) rA0 = Ne - 1;
  int rA1 = r0 + ra + 16; if (rA1 > Ne - 1) rA1 = Ne - 1;
  int t0 = row_info[base + rA0];
  int t1 = row_info[base + rA1];
  const char* gA0 = (const char*)(xb + (size_t)t0 * HDIM) + ca;
  const char* gA1 = (const char*)(xb + (size_t)t1 * HDIM) + ca;
  const char* gB0 = (const char*)(w1b + (size_t)g * IDIM * HDIM + (size_t)(n0 + ra) * HDIM) + ca;
  const char* gB1 = (const char*)(w1b + (size_t)g * IDIM * HDIM + (size_t)(n0 + ra + 16) * HDIM) + ca;
  int aoff = w * 2048;
  int boff = 8192 + w * 2048;
  int lm = ln & 15, lq = ln >> 4;
  int rdA = ((w >> 1) * 64 + lm) * 64 + lq * 16;
  int rdB = 8192 + ((w & 1) * 64 + lm) * 64 + lq * 16;
  floatx4 acc[4][4] = {};
  gload16(gA0, smem + aoff);
  gload16(gA1, smem + aoff + 1024);
  gload16(gB0, smem + boff);
  gload16(gB1, smem + boff + 1024);
  const int NK = HDIM / 32;
  for (int kt = 0; kt < NK; kt++) {
    char* cbuf = smem + (kt & 1) * 16384;
    char* nbuf = smem + ((kt + 1) & 1) * 16384;
    __syncthreads();
    if (kt + 1 < NK) {
      int kb = (kt + 1) * 64;
      gload16(gA0 + kb, nbuf + aoff);
      gload16(gA1 + kb, nbuf + aoff + 1024);
      gload16(gB0 + kb, nbuf + boff);
      gload16(gB1 + kb, nbuf + boff + 1024);
    }
    bf16x8 af[4], bfv[4];
#pragma unroll
    for (int mi = 0; mi < 4; mi++) af[mi] = *(const bf16x8*)(cbuf + rdA + mi * 1024);
#pragma unroll
    for (int ni = 0; ni < 4; ni++) bfv[ni] = *(const bf16x8*)(cbuf + rdB + ni * 1024);
#pragma unroll
    for (int mi = 0; mi < 4; mi++)
#pragma unroll
      for (int ni = 0; ni < 4; ni++)
        acc[mi][ni] = __builtin_amdgcn_mfma_f32_16x16x32_bf16(af[mi], bfv[ni], acc[mi][ni], 0, 0, 0);
  }
  int colbase = n0 + (w & 1) * 64;
#pragma unroll
  for (int mi = 0; mi < 4; mi++) {
#pragma unroll
    for (int reg = 0; reg < 4; reg++) {
      int rr = r0 + (w >> 1) * 64 + mi * 16 + lq * 4 + reg;
      if (rr < Ne) {
        __bf16* orow = hmid + (size_t)(base + rr - chunk_base) * IDIM;
#pragma unroll
        for (int ni = 0; ni < 4; ni++) {
          int c = colbase + ni * 16 + lm;
          float v = acc[mi][ni][reg] + b1[g * IDIM + c];
          v = v / (1.f + __expf(-v));
          orow[c] = (__bf16)v;
        }
      }
    }
  }
}

// ---------------- GEMM2: out += gate * (hmid @ W2[e]^T + b2[e]) ----------------
__global__ __launch_bounds__(256) void gemm2k(
    const __bf16* __restrict__ hmid, const __bf16* __restrict__ w2b,
    const float* __restrict__ b2, float* __restrict__ out,
    const int* __restrict__ row_info, const float* __restrict__ row_gate,
    const int* __restrict__ goff, const int* __restrict__ tbl,
    const int* __restrict__ ntb, int chunk_base) {
  __shared__ __attribute__((aligned(16))) char smem[32768];
  if ((int)blockIdx.x >= ntb[0]) return;
  int info = tbl[blockIdx.x];
  int g = info >> 8, br = info & 255;
  int base = goff[g];
  int Ne = goff[g + 1] - base;
  int r0 = br * 128;
  if (r0 >= Ne) return;
  int n0 = blockIdx.y * 128;
  int tid = threadIdx.x, w = tid >> 6, ln = tid & 63;
  int ra = w * 32 + (ln >> 2);
  int ca = (ln & 3) * 16;
  int rA0 = r0 + ra;      if (rA0 > Ne - 1) rA0 = Ne - 1;
  int rA1 = r0 + ra + 16; if (rA1 > Ne - 1) rA1 = Ne - 1;
  const char* gA0 = (const char*)(hmid + (size_t)(base + rA0 - chunk_base) * IDIM) + ca;
  const char* gA1 = (const char*)(hmid + (size_t)(base + rA1 - chunk_base) * IDIM) + ca;
  const char* gB0 = (const char*)(w2b + (size_t)g * HDIM * IDIM + (size_t)(n0 + ra) * IDIM) + ca;
  const char* gB1 = (const char*)(w2b + (size_t)g * HDIM * IDIM + (size_t)(n0 + ra + 16) * IDIM) + ca;
  int aoff = w * 2048;
  int boff = 8192 + w * 2048;
  int lm = ln & 15, lq = ln >> 4;
  int rdA = ((w >> 1) * 64 + lm) * 64 + lq * 16;
  int rdB = 8192 + ((w & 1) * 64 + lm) * 64 + lq * 16;
  floatx4 acc[4][4] = {};
  gload16(gA0, smem + aoff);
  gload16(gA1, smem + aoff + 1024);
  gload16(gB0, smem + boff);
  gload16(gB1, smem + boff + 1024);
  const int NK = IDIM / 32;
  for (int kt = 0; kt < NK; kt++) {
    char* cbuf = smem + (kt & 1) * 16384;
    char* nbuf = smem + ((kt + 1) & 1) * 16384;
    __syncthreads();
    if (kt + 1 < NK) {
      int kb = (kt + 1) * 64;
      gload16(gA0 + kb, nbuf + aoff);
      gload16(gA1 + kb, nbuf + aoff + 1024);
      gload16(gB0 + kb, nbuf + boff);
      gload16(gB1 + kb, nbuf + boff + 1024);
    }
    bf16x8 af[4], bfv[4];
#pragma unroll
    for (int mi = 0; mi < 4; mi++) af[mi] = *(const bf16x8*)(cbuf + rdA + mi * 1024);
#pragma unroll
    for (int ni = 0; ni < 4; ni++) bfv[ni] = *(const bf16x8*)(cbuf + rdB + ni * 1024);
#pragma unroll
    for (int mi = 0; mi < 4; mi++)
#pragma unroll
      for (int ni = 0; ni < 4; ni++)
        acc[mi][ni] = __builtin_amdgcn_mfma_f32_16x16x32_bf16(af[mi], bfv[ni], acc[mi][ni], 0, 0, 0);
  }
  int colbase = n0 + (w & 1) * 64;
#pragma unroll
  for (int mi = 0; mi < 4; mi++) {
#pragma unroll
    for (int reg = 0; reg < 4; reg++) {
      int rr = r0 + (w >> 1) * 64 + mi * 16 + lq * 4 + reg;
      if (rr < Ne) {
        int t = row_info[base + rr];
        float gate = row_gate[base + rr];
        float* orow = out + (size_t)t * HDIM;
#pragma unroll
        for (int ni = 0; ni < 4; ni++) {
          int c = colbase + ni * 16 + lm;
          float v = gate * (acc[mi][ni][reg] + b2[g * HDIM + c]);
          atomicAdd(&orow[c], v);
        }
      }
    }
  }
}

extern "C" void kernel_launch(void* const* d_in, const int* in_sizes, int n_in,
                              void* d_out, int out_size, void* d_ws, size_t ws_size,
                              hipStream_t stream) {
  (void)in_sizes; (void)n_in; (void)out_size;
  const float* x  = (const float*)d_in[0];
  const float* Wg = (const float*)d_in[1];
  const float* W1 = (const float*)d_in[2];
  const float* b1 = (const float*)d_in[3];
  const float* W2 = (const float*)d_in[4];
  const float* b2 = (const float*)d_in[5];
  float* out = (float*)d_out;
  float* logits = out + (size_t)T_TOK * HDIM;

  const size_t xb_b   = (size_t)T_TOK * HDIM * 2;
  const size_t w_b    = (size_t)NEXP * IDIM * HDIM * 2;
  const size_t side_b = (size_t)2 * T_TOK * 4;
  const size_t meta_b = 32768;
  // CH=2: hmid chunk ~134MB -> L3-resident between gemm1 (producer) and
  // gemm2's 8 column passes (consumer).
  int CH = 2;
  while (CH < 16) {
    size_t hm = ((size_t)((2 * T_TOK) / CH) + 128) * IDIM * 2;
    size_t need = xb_b + 2 * w_b + hm + 4 * side_b + meta_b + 8192;
    if (need <= ws_size) break;
    CH *= 2;
  }
  const int R = (2 * T_TOK) / CH;

  char* p = (char*)d_ws;
  size_t off = 0;
  auto take = [&](size_t bytes) -> char* {
    char* r = p + off;
    off = (off + bytes + 255) & ~(size_t)255;
    return r;
  };
  __bf16* xb   = (__bf16*)take(xb_b);
  __bf16* w1b  = (__bf16*)take(w_b);
  __bf16* w2b  = (__bf16*)take(w_b);
  __bf16* hmid = (__bf16*)take(((size_t)R + 128) * IDIM * 2);
  int*   topk_e   = (int*)take(side_b);
  float* topk_g   = (float*)take(side_b);
  int*   row_info = (int*)take(side_b);
  float* row_gate = (float*)take(side_b);
  int*   gcount   = (int*)take(16 * 4);
  int*   goff     = (int*)take(17 * 4);
  int*   gcur     = (int*)take(16 * 4);
  int*   ntb      = (int*)take(16 * 4);
  int*   tbl      = (int*)take(16 * 288 * 4);

  hipMemsetAsync(gcount, 0, 16 * 4, stream);
  hipMemsetAsync(out, 0, (size_t)T_TOK * HDIM * 4, stream);

  cvtk<<<(T_TOK * HDIM / 8) / 256, 256, 0, stream>>>(x, xb, T_TOK * HDIM / 8);
  cvtk<<<(NEXP * IDIM * HDIM / 8) / 256, 256, 0, stream>>>(W1, w1b, NEXP * IDIM * HDIM / 8);
  cvtk<<<(NEXP * IDIM * HDIM / 8) / 256, 256, 0, stream>>>(W2, w2b, NEXP * IDIM * HDIM / 8);
  routerk<<<T_TOK / 64, 256, 0, stream>>>(x, Wg, logits, topk_e, topk_g, gcount);
  prefixk<<<1, 64, 0, stream>>>(gcount, goff, gcur, tbl, ntb, CH);
  scatterk<<<T_TOK / 256, 256, 0, stream>>>(topk_e, topk_g, gcur, row_info, row_gate);

  int gx = R / 128 + 8;
  for (int c = 0; c < CH; c++) {
    gemm1k<<<dim3(gx, IDIM / 128, 1), 256, 0, stream>>>(
        xb, w1b, b1, hmid, row_info, goff, tbl + c * 288, ntb + c, c * R);
    gemm2k<<<dim3(gx, HDIM / 128, 1), 256, 0, stream>>>(
        hmid, w2b, b2, out, row_info, row_gate, goff, tbl + c * 288, ntb + c, c * R);
  }
}